// Round 7
// baseline (1410.696 us; speedup 1.0000x reference)
//
#include <hip/hip_runtime.h>
#include <stdint.h>

typedef __attribute__((ext_vector_type(8))) short short8;
typedef __attribute__((ext_vector_type(8))) unsigned short ushort8;
typedef __attribute__((ext_vector_type(4))) float f32x4;

#define MFMA(a,b,c) __builtin_amdgcn_mfma_f32_16x16x32_bf16((a),(b),(c),0,0,0)

__device__ __forceinline__ unsigned short f2bf(float f) {
  union { float f; unsigned u; } v; v.f = f;
  unsigned r = v.u + 0x7fffu + ((v.u >> 16) & 1u);
  return (unsigned short)(r >> 16);
}
__device__ __forceinline__ float bf2f(unsigned short s) {
  union { unsigned u; float f; } v; v.u = ((unsigned)s) << 16;
  return v.f;
}

// async global->LDS 16B: LDS dest is wave-uniform base + lane*16; global src per-lane
__device__ __forceinline__ void g2l16(const unsigned short* g, unsigned short* l) {
  __builtin_amdgcn_global_load_lds(
      (const __attribute__((address_space(1))) unsigned int*)(g),
      (__attribute__((address_space(3))) unsigned int*)(l), 16, 0, 0);
}

// V LDS swizzle: row c (128B = 32 banks), spread keys by high-and-low c bits.
__device__ __forceinline__ int vswz(int c, int key) {
  return key ^ ((((c >> 3) ^ c) & 7) << 3);
}

// ---------------- NCHW fp32 -> NHWC bf16 transpose (64x64 tiles) -----------
__global__ void nhwc_kernel(const float* __restrict__ src, unsigned short* __restrict__ dst) {
  __shared__ unsigned short T[64][72];   // stride 144B (16B aligned rows)
  int p0 = blockIdx.x * 64, c0 = blockIdx.y * 64, bb = blockIdx.z;
  const float* S = src + (size_t)bb * 384 * 36864;
  unsigned short* D = dst + (size_t)bb * 36864 * 384;
  int t = threadIdx.x;          // 256
  int pl = (t & 15) * 4;        // p offset (float4)
  int r0 = t >> 4;              // 16 c-rows per pass
#pragma unroll
  for (int k = 0; k < 4; ++k) {
    int c = r0 + 16 * k;
    float4 v = *(const float4*)&S[(size_t)(c0 + c) * 36864 + p0 + pl];
    T[pl + 0][c] = f2bf(v.x); T[pl + 1][c] = f2bf(v.y);
    T[pl + 2][c] = f2bf(v.z); T[pl + 3][c] = f2bf(v.w);
  }
  __syncthreads();
  int row = t >> 2, ch = (t & 3) * 16;
  ushort8 a = *(const ushort8*)&T[row][ch];
  ushort8 b = *(const ushort8*)&T[row][ch + 8];
  uint4* d = (uint4*)&D[(size_t)(p0 + row) * 384 + c0 + ch];
  d[0] = *(uint4*)&a; d[1] = *(uint4*)&b;
}

// ---------------- prep: fold BN into 1x1 weights, attn scale into q rows ----
__global__ void fold_qvk_kernel(const float* __restrict__ qv_w, const float* __restrict__ qv_b,
                                const float* __restrict__ k_w, const float* __restrict__ k_b,
                                const float* __restrict__ g, const float* __restrict__ be,
                                const float* __restrict__ mu, const float* __restrict__ var,
                                unsigned short* __restrict__ Wq, float* __restrict__ bq,
                                unsigned short* __restrict__ Wk, float* __restrict__ bk) {
  int o = blockIdx.x;            // 0..767 -> qv row, 768..1151 -> k row
  int t = threadIdx.x;           // 128
  bool isq = o < 768;
  int oo = isq ? o : o - 768;
  const float* wrow = isq ? qv_w + (size_t)oo * 384 : k_w + (size_t)oo * 384;
  float mul = (isq && oo < 384) ? 0.08838834764831845f : 1.0f;  // 1/sqrt(128) folded into q
  float acc = 0.f;
  for (int c = t; c < 384; c += 128) {
    float sc = g[c] * rsqrtf(var[c] + 1e-5f);
    float sh = be[c] - mu[c] * sc;
    float w = wrow[c];
    acc += w * sh;
    unsigned short wb = f2bf(w * sc * mul);
    if (isq) Wq[(size_t)oo * 384 + c] = wb; else Wk[(size_t)oo * 384 + c] = wb;
  }
#pragma unroll
  for (int m = 1; m < 64; m <<= 1) acc += __shfl_xor(acc, m);
  __shared__ float part[2];
  if ((t & 63) == 0) part[t >> 6] = acc;
  __syncthreads();
  if (t == 0) {
    float b0 = isq ? qv_b[oo] : k_b[oo];
    float bias = (b0 + part[0] + part[1]) * mul;
    if (isq) bq[oo] = bias; else bk[oo] = bias;
  }
}

// reorder oc_w (o,c,kh,kw) -> Wc[o][kq][c] bf16 ; compute output-BN scale/shift
__global__ void fold_oc_kernel(const float* __restrict__ oc_w,
                               const float* __restrict__ g, const float* __restrict__ be,
                               const float* __restrict__ mu, const float* __restrict__ var,
                               unsigned short* __restrict__ Wc, float* __restrict__ s_oc,
                               float* __restrict__ t_oc) {
  int idx = blockIdx.x * 256 + threadIdx.x;
  if (idx < 384) {
    float sc = g[idx] * rsqrtf(var[idx] + 1e-5f);
    s_oc[idx] = sc;
    t_oc[idx] = be[idx] - mu[idx] * sc;
  }
  if (idx < 384 * 3456) {
    int o = idx / 3456, r = idx % 3456;
    int kq = r / 384, c = r % 384;
    Wc[idx] = f2bf(oc_w[((size_t)o * 384 + c) * 9 + kq]);
  }
}

// ------- 1x1 GEMM on bf16 NHWC: 2-phase dbuf g2l16, 256p x 128o, BK=32 -----
__launch_bounds__(512)
__global__ void gemm1n_kernel(const unsigned short* __restrict__ XN, const unsigned short* __restrict__ W,
                              const float* __restrict__ bias, unsigned short* __restrict__ Out,
                              int OW, int OT) {
  int nwg = gridDim.x;
  int bid = blockIdx.x;
  int bi = (bid & 7) * (nwg >> 3) + (bid >> 3);   // XCD-contiguous (nwg % 8 == 0)
  int ot = bi % OT;                                // ot innermost: X panel L2 reuse
  int pt = (bi / OT) % 144;
  int bb = bi / (OT * 144);
  int obase = ot * 128, pbase = pt * 256;
  __shared__ unsigned short Ws2[2][128 * 32];
  __shared__ unsigned short Xs2[2][256 * 32];
  int tid = threadIdx.x;
  int wv = tid >> 6, lane = tid & 63;
  int l15 = lane & 15, lg = lane >> 4;
  int wc = wv & 1, wr = wv >> 1;
  f32x4 acc[4][4];
#pragma unroll
  for (int i = 0; i < 4; ++i)
#pragma unroll
    for (int j = 0; j < 4; ++j) acc[i][j] = 0.f;
  int rl = lane >> 2;
  int csw = (((lane & 3) ^ ((lane >> 3) & 3)) << 3);
  const unsigned short* Ap = W + (size_t)(obase + 16 * wv + rl) * 384 + csw;
  const unsigned short* XbN = XN + (size_t)bb * 36864 * 384;
  const unsigned short* Bp0 = XbN + (size_t)(pbase + 32 * wv + rl) * 384 + csw;
  const unsigned short* Bp1 = Bp0 + (size_t)16 * 384;
  int colsw = ((lg ^ ((l15 >> 1) & 3)) << 3);
  unsigned short* WsW = &Ws2[0][(16 * wv) * 32];
  unsigned short* XsW0 = &Xs2[0][(32 * wv) * 32];
  unsigned short* XsW1 = &Xs2[0][(32 * wv + 16) * 32];
  const int WBUF = 128 * 32, XBUF = 256 * 32;
  g2l16(Ap, WsW); g2l16(Bp0, XsW0); g2l16(Bp1, XsW1);
  Ap += 32; Bp0 += 32; Bp1 += 32;
  for (int t = 0; t < 12; ++t) {
    int cur = t & 1, nxt = cur ^ 1;
    if (t < 11) {
      g2l16(Ap, WsW + nxt * WBUF);
      g2l16(Bp0, XsW0 + nxt * XBUF);
      g2l16(Bp1, XsW1 + nxt * XBUF);
      Ap += 32; Bp0 += 32; Bp1 += 32;
      asm volatile("s_waitcnt vmcnt(3)" ::: "memory");
    } else {
      asm volatile("s_waitcnt vmcnt(0)" ::: "memory");
    }
    __builtin_amdgcn_s_barrier();
    __builtin_amdgcn_sched_barrier(0);
    const unsigned short* Wt = &Ws2[cur][0];
    const unsigned short* Xt = &Xs2[cur][0];
    short8 af[4], bf[4];
#pragma unroll
    for (int f = 0; f < 4; ++f) af[f] = *(const short8*)&Xt[(wr * 64 + f * 16 + l15) * 32 + colsw];
#pragma unroll
    for (int f = 0; f < 4; ++f) bf[f] = *(const short8*)&Wt[(wc * 64 + f * 16 + l15) * 32 + colsw];
#pragma unroll
    for (int fm = 0; fm < 4; ++fm)
#pragma unroll
      for (int fn = 0; fn < 4; ++fn)
        acc[fm][fn] = MFMA(af[fm], bf[fn], acc[fm][fn]);
    __builtin_amdgcn_s_barrier();
    __builtin_amdgcn_sched_barrier(0);
  }
  unsigned short* Ob = Out + (size_t)bb * 36864 * OW;
#pragma unroll
  for (int fn = 0; fn < 4; ++fn) {
    int o = obase + wc * 64 + fn * 16 + l15;
    float bsv = bias[o];
#pragma unroll
    for (int fm = 0; fm < 4; ++fm) {
#pragma unroll
      for (int r = 0; r < 4; ++r) {
        int p = pbase + wr * 64 + fm * 16 + lg * 4 + r;
        Ob[(size_t)p * OW + o] = f2bf(acc[fm][fn][r] + bsv);
      }
    }
  }
}

// ---------------- GEMM-1 fallback (fp32 NCHW input, round-1 path) ----------
__launch_bounds__(256)
__global__ void gemm1_kernel(const float* __restrict__ X, const unsigned short* __restrict__ W,
                             const float* __restrict__ bias, unsigned short* __restrict__ Out,
                             int OW, int OT) {
  int bi = blockIdx.x;
  int ot = bi % OT;
  int pt = (bi / OT) % 288;
  int bb = bi / (OT * 288);
  int obase = ot * 128, pbase = pt * 128;
  __shared__ unsigned short As[128 * 40];
  __shared__ unsigned short Bs[128 * 40];
  int tid = threadIdx.x;
  int wv = tid >> 6, lane = tid & 63;
  int l15 = lane & 15, lg = lane >> 4;
  int pw = (wv >> 1) * 64, ow = (wv & 1) * 64;
  f32x4 acc[4][4];
#pragma unroll
  for (int i = 0; i < 4; ++i)
#pragma unroll
    for (int j = 0; j < 4; ++j) acc[i][j] = 0.f;
  const float* Xb = X + (size_t)bb * 384 * 36864;
  int arow = tid >> 1, ahalf = tid & 1;
  int bp = tid & 127, bcg0 = tid >> 7;
  for (int ks = 0; ks < 12; ++ks) {
    int c0 = ks * 32;
    __syncthreads();
    {
      const uint4* s4 = (const uint4*)(W + (size_t)(obase + arow) * 384 + c0 + ahalf * 16);
      uint4 a0 = s4[0], a1 = s4[1];
      uint4* d = (uint4*)&As[arow * 40 + ahalf * 16];
      d[0] = a0; d[1] = a1;
    }
    {
#pragma unroll
      for (int q = 0; q < 2; ++q) {
        int cg = bcg0 + q * 2;
        int cc = c0 + cg * 8;
        const float* src = Xb + (size_t)cc * 36864 + pbase + bp;
        ushort8 t8;
#pragma unroll
        for (int j = 0; j < 8; ++j) t8[j] = f2bf(src[(size_t)j * 36864]);
        *(ushort8*)&Bs[bp * 40 + cg * 8] = t8;
      }
    }
    __syncthreads();
    short8 af[4], bf[4];
#pragma unroll
    for (int f = 0; f < 4; ++f) af[f] = *(const short8*)&Bs[(pw + f * 16 + l15) * 40 + lg * 8];
#pragma unroll
    for (int f = 0; f < 4; ++f) bf[f] = *(const short8*)&As[(ow + f * 16 + l15) * 40 + lg * 8];
#pragma unroll
    for (int fm = 0; fm < 4; ++fm)
#pragma unroll
      for (int fn = 0; fn < 4; ++fn)
        acc[fm][fn] = MFMA(af[fm], bf[fn], acc[fm][fn]);
  }
  unsigned short* Ob = Out + (size_t)bb * 36864 * OW;
#pragma unroll
  for (int fn = 0; fn < 4; ++fn) {
    int o = obase + ow + fn * 16 + l15;
    float bsv = bias[o];
#pragma unroll
    for (int fm = 0; fm < 4; ++fm) {
#pragma unroll
      for (int r = 0; r < 4; ++r) {
        int p = pbase + pw + fm * 16 + lg * 4 + r;
        Ob[(size_t)p * OW + o] = f2bf(acc[fm][fn][r] + bsv);
      }
    }
  }
}

// ---------------- windowed attention (flash-style), MODE 0/1/2 -------------
// padded=1: residual from rgbn (bf16 NHWC), store into Xpad at (h+1,w+1).
// padded=0: residual from rgb (fp32 NCHW), store into qv q-region.
template <int MODE>
__launch_bounds__(256)
__global__ void attn_kernel(const unsigned short* qv, const unsigned short* kx,
                            const float* __restrict__ rgb, const unsigned short* __restrict__ rgbn,
                            unsigned short* xout, int padded) {
  constexpr int GB = MODE * 128;
  constexpr int NKV = (MODE == 2) ? 4 : 1;
  constexpr int NKF = (MODE == 0) ? 1 : 4;
  int bi = blockIdx.x;
  int bb = bi / 576;
  int r5 = bi % 576;
  int tid = threadIdx.x;
  int wv = tid >> 6, lane = tid & 63;
  int l15 = lane & 15, lg = lane >> 4;

  int h0, w0, qtb;
  if (MODE == 0) { int wy = r5 / 12; int wxb = (r5 % 12) * 4; h0 = wy * 4; w0 = wxb * 4; qtb = 0; }
  else if (MODE == 1) { int wy = r5 / 24; int wx = r5 % 24; h0 = wy * 8; w0 = wx * 8; qtb = 0; }
  else { int win = r5 >> 2; int qt = r5 & 3; int wy = win / 12; int wx = win % 12; h0 = wy * 16; w0 = wx * 16; qtb = qt * 64; }

  auto tok2p = [&](int t) -> int {
    if (MODE == 0) { int lw = t >> 4, tt = t & 15; return (h0 + (tt >> 2)) * 192 + w0 + lw * 4 + (tt & 3); }
    else if (MODE == 1) { return (h0 + (t >> 3)) * 192 + w0 + (t & 7); }
    else { return (h0 + (t >> 4)) * 192 + w0 + (t & 15); }
  };

  __shared__ unsigned short Qs[64 * 128];   // [tok][c] xor-swizzled
  __shared__ unsigned short Ks[64 * 128];   // [key][c] xor-swizzled
  __shared__ unsigned short Vst[128 * 64];  // [c][key] vswz
  __shared__ unsigned short Ps[4 * 16 * 72];

  const unsigned short* qvB = qv + (size_t)bb * 36864 * 768;
  const unsigned short* kB = kx + (size_t)bb * 36864 * 384;

  // stage Q (64 tokens x 128 c)
  for (int ch = tid; ch < 1024; ch += 256) {
    int tok = ch >> 4, c8 = (ch & 15) << 3;
    int p = tok2p(qtb + tok);
    uint4 v = *(const uint4*)(qvB + (size_t)p * 768 + GB + c8);
    *(uint4*)&Qs[tok * 128 + (c8 ^ ((tok & 7) << 3))] = v;
  }
  __syncthreads();
  short8 qf[4];
  {
    int qrow = wv * 16 + l15;
#pragma unroll
    for (int cs = 0; cs < 4; ++cs)
      qf[cs] = *(const short8*)&Qs[qrow * 128 + ((cs * 32 + lg * 8) ^ ((qrow & 7) << 3))];
  }

  float m[4], s[4];
#pragma unroll
  for (int r = 0; r < 4; ++r) { m[r] = -1e30f; s[r] = 0.f; }
  f32x4 oacc[8];
#pragma unroll
  for (int i = 0; i < 8; ++i) oacc[i] = 0.f;

  for (int kt = 0; kt < NKV; ++kt) {
    __syncthreads();
    for (int ch = tid; ch < 1024; ch += 256) {  // stage K tile
      int tok = ch >> 4, c8 = (ch & 15) << 3;
      int p = tok2p(kt * 64 + tok);
      uint4 v = *(const uint4*)(kB + (size_t)p * 384 + GB + c8);
      *(uint4*)&Ks[tok * 128 + (c8 ^ ((tok & 7) << 3))] = v;
    }
    for (int ch = tid; ch < 1024; ch += 256) {  // stage V tile (transposed)
      int key = ch >> 4, c8 = (ch & 15) << 3;
      int p = tok2p(kt * 64 + key);
      ushort8 v = *(const ushort8*)(qvB + (size_t)p * 768 + 384 + GB + c8);
#pragma unroll
      for (int j = 0; j < 8; ++j)
        Vst[(c8 + j) * 64 + vswz(c8 + j, key)] = v[j];
    }
    __syncthreads();

    f32x4 sc[NKF];
#pragma unroll
    for (int kfi = 0; kfi < NKF; ++kfi) {
      int kf = (MODE == 0) ? wv : kfi;
      int krow = kf * 16 + l15;
      f32x4 a; a = 0.f;
#pragma unroll
      for (int cs = 0; cs < 4; ++cs) {
        short8 kfr = *(const short8*)&Ks[krow * 128 + ((cs * 32 + lg * 8) ^ ((krow & 7) << 3))];
        a = MFMA(qf[cs], kfr, a);
      }
      sc[kfi] = a;
    }

    unsigned short* Pw = Ps + wv * (16 * 72);
    float pr[4][NKF];
#pragma unroll
    for (int r = 0; r < 4; ++r) {
      float mx = -1e30f;
#pragma unroll
      for (int kfi = 0; kfi < NKF; ++kfi) mx = fmaxf(mx, sc[kfi][r]);
#pragma unroll
      for (int d = 1; d < 16; d <<= 1) mx = fmaxf(mx, __shfl_xor(mx, d));
      float mn = fmaxf(m[r], mx);
      float f = __expf(m[r] - mn);
      float ls = 0.f;
#pragma unroll
      for (int kfi = 0; kfi < NKF; ++kfi) { float e = __expf(sc[kfi][r] - mn); pr[r][kfi] = e; ls += e; }
#pragma unroll
      for (int d = 1; d < 16; d <<= 1) ls += __shfl_xor(ls, d);
      s[r] = s[r] * f + ls;
      m[r] = mn;
#pragma unroll
      for (int ct = 0; ct < 8; ++ct) oacc[ct][r] *= f;
    }
#pragma unroll
    for (int r = 0; r < 4; ++r) {
      int prow = lg * 4 + r;
#pragma unroll
      for (int kfi = 0; kfi < NKF; ++kfi) {
        int pcol = (MODE == 0) ? l15 : kfi * 16 + l15;
        Pw[prow * 72 + pcol] = f2bf(pr[r][kfi]);
      }
      if (MODE == 0) Pw[prow * 72 + 16 + l15] = 0;
    }
    constexpr int nks = (MODE == 0) ? 1 : 2;
#pragma unroll
    for (int ks = 0; ks < nks; ++ks) {
      short8 pf = *(const short8*)&Pw[l15 * 72 + ks * 32 + lg * 8];
#pragma unroll
      for (int ct = 0; ct < 8; ++ct) {
        int c = ct * 16 + l15;
        short8 vf;
        if (MODE == 0) {
          if (lg < 2) vf = *(const short8*)&Vst[c * 64 + vswz(c, wv * 16 + lg * 8)];
          else vf = 0;
        } else {
          vf = *(const short8*)&Vst[c * 64 + vswz(c, ks * 32 + lg * 8)];
        }
        oacc[ct] = MFMA(pf, vf, oacc[ct]);
      }
    }
  }

  // epilogue: divide by sum, add residual, store x (bf16)
  const float* rgbB = rgb + (size_t)bb * 384 * 36864;
  const unsigned short* rgbNB = rgbn + (size_t)bb * 36864 * 384;
  unsigned short* xB = padded ? xout + (size_t)bb * 37636 * 384
                              : xout + (size_t)bb * 36864 * 768;
#pragma unroll
  for (int r = 0; r < 4; ++r) {
    int q64 = wv * 16 + lg * 4 + r;
    int p = tok2p(qtb + q64);
    float inv = 1.0f / s[r];
    size_t rowoff;
    if (padded) {
      int h = p / 192, w = p % 192;
      rowoff = (size_t)((h + 1) * 194 + (w + 1)) * 384;
    } else {
      rowoff = (size_t)p * 768;
    }
#pragma unroll
    for (int ct = 0; ct < 8; ++ct) {
      int c = GB + ct * 16 + l15;
      float res = padded ? bf2f(rgbNB[(size_t)p * 384 + c]) : rgbB[(size_t)c * 36864 + p];
      float val = oacc[ct][r] * inv + res;
      xB[rowoff + c] = f2bf(val);
    }
  }
}

// ------- zero only the 1-pixel border of xpad ------------------------------
__global__ void zero_border_kernel(unsigned short* __restrict__ xpad) {
  int bi = blockIdx.x;            // 4 * 772
  int bb = bi / 772, i = bi % 772;
  int h, w;
  if (i < 194) { h = 0; w = i; }
  else if (i < 388) { h = 193; w = i - 194; }
  else if (i < 580) { w = 0; h = i - 388 + 1; }
  else { w = 193; h = i - 580 + 1; }
  int t = threadIdx.x;            // 64; 48 active
  if (t < 48) {
    uint4 z = {0, 0, 0, 0};
    uint4* row = (uint4*)(xpad + ((size_t)bb * 37636 + h * 194 + w) * 384);
    row[t] = z;
  }
}

// ------ 3x3 conv: 2-phase dbuf, 4 waves, 64o x 128p per-wave tile ----------
// Same 128o x 256p block tile / 49KB LDS / zero-conflict swizzle as the
// verified round-5 conv3d, but 4 waves with acc[4][8] (32 MFMA per K-step per
// wave, 2x density) so the 2 barriers per step amortize over twice the MFMA.
// Staging: 6 g2l16 issues/wave/step (A rows 32wv..+31, B rows 64wv..+63),
// counted vmcnt(6) keeps the next step's loads in flight.
__launch_bounds__(256)
__global__ void conv3f_kernel(const unsigned short* __restrict__ Xp,  // [b][37636][384] zero-padded
                              const unsigned short* __restrict__ Wc,
                              const float* __restrict__ s_oc, const float* __restrict__ t_oc,
                              float* __restrict__ Out) {
  int bid = blockIdx.x;
  int bi = (bid & 7) * 216 + (bid >> 3);   // XCD-contiguous
  int ot = bi % 3;                          // ot innermost: X panel L2 reuse
  int pt = (bi / 3) % 144;
  int bb = bi / 432;
  int obase = ot * 128, pbase = pt * 256;
  __shared__ unsigned short Ws2[2][128 * 32];
  __shared__ unsigned short Xs2[2][256 * 32];
  int tid = threadIdx.x;
  int wv = tid >> 6, lane = tid & 63;       // 4 waves
  int l15 = lane & 15, lg = lane >> 4;
  int wc = wv & 1, wr = wv >> 1;            // wave tile: 64 o x 128 p
  f32x4 acc[4][8];
#pragma unroll
  for (int i = 0; i < 4; ++i)
#pragma unroll
    for (int j = 0; j < 8; ++j) acc[i][j] = 0.f;
  int rl = lane >> 2;
  int csw = (((lane & 3) ^ ((lane >> 3) & 3)) << 3);  // staging source chunk swizzle
  // A: wave stages rows 32wv..32wv+31 (2 issues)
  const unsigned short* Ap0 = Wc + (size_t)(obase + 32 * wv + rl) * 3456 + csw;
  const unsigned short* Ap1 = Ap0 + (size_t)16 * 3456;
  // B: wave stages rows 64wv..64wv+63 (4 issues)
  const unsigned short* Xb = Xp + (size_t)bb * 37636 * 384;
  const unsigned short* Bp[4];
#pragma unroll
  for (int j = 0; j < 4; ++j) {
    int p = pbase + 64 * wv + 16 * j + rl;
    Bp[j] = Xb + (size_t)((p / 192 + 1) * 194 + (p % 192 + 1) - 195) * 384 + csw;
  }
  int colsw = ((lg ^ ((l15 >> 1) & 3)) << 3);  // read-side swizzle (loop-invariant)
  unsigned short* AsW0 = &Ws2[0][(32 * wv) * 32];
  unsigned short* AsW1 = &Ws2[0][(32 * wv + 16) * 32];
  unsigned short* XsW0 = &Xs2[0][(64 * wv) * 32];
  unsigned short* XsW1 = &Xs2[0][(64 * wv + 16) * 32];
  unsigned short* XsW2 = &Xs2[0][(64 * wv + 32) * 32];
  unsigned short* XsW3 = &Xs2[0][(64 * wv + 48) * 32];
  const int WBUF = 128 * 32, XBUF = 256 * 32;
  // prologue: stage step 0 into buf 0
  g2l16(Ap0, AsW0); g2l16(Ap1, AsW1);
  g2l16(Bp[0], XsW0); g2l16(Bp[1], XsW1); g2l16(Bp[2], XsW2); g2l16(Bp[3], XsW3);
  Ap0 += 32; Ap1 += 32;
#pragma unroll
  for (int j = 0; j < 4; ++j) Bp[j] += 32;
  int aoff = (wc * 64 + l15) * 32 + colsw;
  int boff = (wr * 128 + l15) * 32 + colsw;
  for (int t = 0; t < 108; ++t) {
    int cur = t & 1, nxt = cur ^ 1;
    if (t < 107) {
      g2l16(Ap0, AsW0 + nxt * WBUF); g2l16(Ap1, AsW1 + nxt * WBUF);
      g2l16(Bp[0], XsW0 + nxt * XBUF); g2l16(Bp[1], XsW1 + nxt * XBUF);
      g2l16(Bp[2], XsW2 + nxt * XBUF); g2l16(Bp[3], XsW3 + nxt * XBUF);
      Ap0 += 32; Ap1 += 32;
#pragma unroll
      for (int j = 0; j < 4; ++j) Bp[j] += 32;
      if (t == 34 || t == 70) {
#pragma unroll
        for (int j = 0; j < 4; ++j) Bp[j] += 73344;  // tap-row jump (191*384)
      }
      asm volatile("s_waitcnt vmcnt(6)" ::: "memory");  // drain step-t tile, keep next in flight
    } else {
      asm volatile("s_waitcnt vmcnt(0)" ::: "memory");
    }
    __builtin_amdgcn_s_barrier();
    __builtin_amdgcn_sched_barrier(0);
    const unsigned short* Wt = &Ws2[cur][0];
    const unsigned short* Xt = &Xs2[cur][0];
    short8 af[4], bf2[8];
#pragma unroll
    for (int f = 0; f < 4; ++f) af[f] = *(const short8*)&Wt[aoff + f * 512];
#pragma unroll
    for (int f = 0; f < 8; ++f) bf2[f] = *(const short8*)&Xt[boff + f * 512];
#pragma unroll
    for (int fm = 0; fm < 4; ++fm)
#pragma unroll
      for (int fn = 0; fn < 8; ++fn)
        acc[fm][fn] = MFMA(af[fm], bf2[fn], acc[fm][fn]);
    __builtin_amdgcn_s_barrier();
    __builtin_amdgcn_sched_barrier(0);
  }
  float* Ob = Out + (size_t)bb * 384 * 36864;
#pragma unroll
  for (int fm = 0; fm < 4; ++fm) {
#pragma unroll
    for (int r = 0; r < 4; ++r) {
      int o = obase + wc * 64 + fm * 16 + lg * 4 + r;
      float sv = s_oc[o], tv = t_oc[o];
#pragma unroll
      for (int fn = 0; fn < 8; ++fn) {
        int p = pbase + wr * 128 + fn * 16 + l15;
        float y = acc[fm][fn][r] * sv + tv;
        Ob[(size_t)o * 36864 + p] = (y >= 0.f) ? y : 0.2f * y;
      }
    }
  }
}

// ---------------- fallback 3x3 conv (bounds-checked, no padding) -----------
__launch_bounds__(256)
__global__ void conv3_kernel(const unsigned short* __restrict__ X,
                             const unsigned short* __restrict__ Wc,
                             const float* __restrict__ s_oc, const float* __restrict__ t_oc,
                             float* __restrict__ Out) {
  int bi = blockIdx.x;
  int pt = bi % 288;
  int ot = (bi / 288) % 3;
  int bb = bi / 864;
  int obase = ot * 128, pbase = pt * 128;
  __shared__ unsigned short As[128 * 40];
  __shared__ unsigned short Bs[128 * 40];
  int tid = threadIdx.x;
  int wv = tid >> 6, lane = tid & 63;
  int l15 = lane & 15, lg = lane >> 4;
  int ow = (wv & 1) * 64, pw = (wv >> 1) * 64;
  f32x4 acc[4][4];
#pragma unroll
  for (int i = 0; i < 4; ++i)
#pragma unroll
    for (int j = 0; j < 4; ++j) acc[i][j] = 0.f;
  int arow = tid >> 1, ahalf = tid & 1;
  int sp = pbase + arow;
  int sh = sp / 192, sw = sp % 192;
  const unsigned short* Xb = X + (size_t)bb * 36864 * 768;
  for (int ksi = 0; ksi < 108; ++ksi) {
    int kq = ksi / 12;
    int c0 = (ksi % 12) * 32;
    int dh = kq / 3 - 1, dw = kq % 3 - 1;
    __syncthreads();
    {
      const uint4* s4 = (const uint4*)(Wc + (size_t)(obase + arow) * 3456 + kq * 384 + c0 + ahalf * 16);
      uint4 a0 = s4[0], a1 = s4[1];
      uint4* d = (uint4*)&As[arow * 40 + ahalf * 16];
      d[0] = a0; d[1] = a1;
    }
    {
      int hh = sh + dh, ww2 = sw + dw;
      uint4 b0 = {0, 0, 0, 0}, b1 = {0, 0, 0, 0};
      if ((unsigned)hh < 192u && (unsigned)ww2 < 192u) {
        const uint4* s4 = (const uint4*)(Xb + (size_t)(hh * 192 + ww2) * 768 + c0 + ahalf * 16);
        b0 = s4[0]; b1 = s4[1];
      }
      uint4* d = (uint4*)&Bs[arow * 40 + ahalf * 16];
      d[0] = b0; d[1] = b1;
    }
    __syncthreads();
    short8 af[4], bf2[4];
#pragma unroll
    for (int f = 0; f < 4; ++f) af[f] = *(const short8*)&As[(ow + f * 16 + l15) * 40 + lg * 8];
#pragma unroll
    for (int f = 0; f < 4; ++f) bf2[f] = *(const short8*)&Bs[(pw + f * 16 + l15) * 40 + lg * 8];
#pragma unroll
    for (int fm = 0; fm < 4; ++fm)
#pragma unroll
      for (int fn = 0; fn < 4; ++fn)
        acc[fm][fn] = MFMA(af[fm], bf2[fn], acc[fm][fn]);
  }
  float* Ob = Out + (size_t)bb * 384 * 36864;
#pragma unroll
  for (int fm = 0; fm < 4; ++fm) {
#pragma unroll
    for (int r = 0; r < 4; ++r) {
      int o = obase + ow + fm * 16 + lg * 4 + r;
      float sv = s_oc[o], tv = t_oc[o];
#pragma unroll
      for (int fn = 0; fn < 4; ++fn) {
        int p = pbase + pw + fn * 16 + l15;
        float y = acc[fm][fn][r] * sv + tv;
        Ob[(size_t)o * 36864 + p] = (y >= 0.f) ? y : 0.2f * y;
      }
    }
  }
}

// ---------------- launch ----------------
extern "C" void kernel_launch(void* const* d_in, const int* in_sizes, int n_in,
                              void* d_out, int out_size, void* d_ws, size_t ws_size,
                              hipStream_t stream) {
  const float* rgb  = (const float*)d_in[0];
  const float* fre  = (const float*)d_in[1];
  const float* ng   = (const float*)d_in[2];
  const float* nb   = (const float*)d_in[3];
  const float* nm   = (const float*)d_in[4];
  const float* nv   = (const float*)d_in[5];
  const float* qv_w = (const float*)d_in[6];
  const float* qv_b = (const float*)d_in[7];
  const float* k_w  = (const float*)d_in[8];
  const float* k_b  = (const float*)d_in[9];
  const float* oc_w = (const float*)d_in[10];
  const float* oc_g = (const float*)d_in[11];
  const float* oc_b = (const float*)d_in[12];
  const float* oc_m = (const float*)d_in[13];
  const float* oc_v = (const float*)d_in[14];

  char* ws = (char*)d_ws;
  const size_t QV_B   = 226492416;   // 147456*768*2
  const size_t K_B    = 113246208;   // 147456*384*2
  const size_t XPAD_B = 115617792;   // 4*37636*384*2  (also holds freN: 113246208 <= this)
  const size_t RGBN_B = 113246208;   // 4*36864*384*2
  size_t off = 0;
  unsigned short* qvbuf = (unsigned short*)(ws + off); off += QV_B;
  unsigned short* kbuf  = (unsigned short*)(ws + off); off += K_B;
  size_t dyn_off = off;
  unsigned short* xpad = (unsigned short*)(ws + dyn_off);          // also freN
  unsigned short* rgbN = (unsigned short*)(ws + dyn_off + XPAD_B);
  const size_t WEIGHTS_B = 589824 + 294912 + 2654208 + 3072 + 1536 + 1536 + 1536;
  bool fast = (ws_size >= dyn_off + XPAD_B + RGBN_B + WEIGHTS_B);
  if (fast) off += XPAD_B + RGBN_B;
  unsigned short* Wq = (unsigned short*)(ws + off); off += 589824;
  unsigned short* Wk = (unsigned short*)(ws + off); off += 294912;
  unsigned short* Wc = (unsigned short*)(ws + off); off += 2654208;
  float* bq  = (float*)(ws + off); off += 3072;
  float* bk  = (float*)(ws + off); off += 1536;
  float* soc = (float*)(ws + off); off += 1536;
  float* toc = (float*)(ws + off); off += 1536;
  float* out = (float*)d_out;

  fold_qvk_kernel<<<dim3(1152), dim3(128), 0, stream>>>(qv_w, qv_b, k_w, k_b, ng, nb, nm, nv, Wq, bq, Wk, bk);
  fold_oc_kernel<<<dim3(5184), dim3(256), 0, stream>>>(oc_w, oc_g, oc_b, oc_m, oc_v, Wc, soc, toc);

  if (fast) {
    unsigned short* freN = xpad;  // region reused: freN dead before xpad written
    nhwc_kernel<<<dim3(576, 6, 4), dim3(256), 0, stream>>>(rgb, rgbN);
    nhwc_kernel<<<dim3(576, 6, 4), dim3(256), 0, stream>>>(fre, freN);
    gemm1n_kernel<<<dim3(3456), dim3(512), 0, stream>>>(rgbN, Wq, bq, qvbuf, 768, 6);
    gemm1n_kernel<<<dim3(1728), dim3(512), 0, stream>>>(freN, Wk, bk, kbuf, 384, 3);
    zero_border_kernel<<<dim3(4 * 772), dim3(64), 0, stream>>>(xpad);
    attn_kernel<0><<<dim3(2304), dim3(256), 0, stream>>>(qvbuf, kbuf, rgb, rgbN, xpad, 1);
    attn_kernel<1><<<dim3(2304), dim3(256), 0, stream>>>(qvbuf, kbuf, rgb, rgbN, xpad, 1);
    attn_kernel<2><<<dim3(2304), dim3(256), 0, stream>>>(qvbuf, kbuf, rgb, rgbN, xpad, 1);
    conv3f_kernel<<<dim3(1728), dim3(256), 0, stream>>>(xpad, Wc, soc, toc, out);
  } else {
    gemm1_kernel<<<dim3(4 * 288 * 6), dim3(256), 0, stream>>>(rgb, Wq, bq, qvbuf, 768, 6);
    gemm1_kernel<<<dim3(4 * 288 * 3), dim3(256), 0, stream>>>(fre, Wk, bk, kbuf, 384, 3);
    attn_kernel<0><<<dim3(2304), dim3(256), 0, stream>>>(qvbuf, kbuf, rgb, qvbuf, qvbuf, 0);
    attn_kernel<1><<<dim3(2304), dim3(256), 0, stream>>>(qvbuf, kbuf, rgb, qvbuf, qvbuf, 0);
    attn_kernel<2><<<dim3(2304), dim3(256), 0, stream>>>(qvbuf, kbuf, rgb, qvbuf, qvbuf, 0);
    conv3_kernel<<<dim3(4 * 3 * 288), dim3(256), 0, stream>>>(qvbuf, Wc, soc, toc, out);
  }
}

// Round 8
// 1178.963 us; speedup vs baseline: 1.1966x; 1.1966x over previous
//
#include <hip/hip_runtime.h>
#include <stdint.h>

typedef __attribute__((ext_vector_type(8))) short short8;
typedef __attribute__((ext_vector_type(8))) unsigned short ushort8;
typedef __attribute__((ext_vector_type(4))) float f32x4;

#define MFMA(a,b,c) __builtin_amdgcn_mfma_f32_16x16x32_bf16((a),(b),(c),0,0,0)

__device__ __forceinline__ unsigned short f2bf(float f) {
  union { float f; unsigned u; } v; v.f = f;
  unsigned r = v.u + 0x7fffu + ((v.u >> 16) & 1u);
  return (unsigned short)(r >> 16);
}
__device__ __forceinline__ float bf2f(unsigned short s) {
  union { unsigned u; float f; } v; v.u = ((unsigned)s) << 16;
  return v.f;
}

// async global->LDS 16B: LDS dest is wave-uniform base + lane*16; global src per-lane
__device__ __forceinline__ void g2l16(const unsigned short* g, unsigned short* l) {
  __builtin_amdgcn_global_load_lds(
      (const __attribute__((address_space(1))) unsigned int*)(g),
      (__attribute__((address_space(3))) unsigned int*)(l), 16, 0, 0);
}

// V LDS swizzle: row c (128B = 32 banks), spread keys by high-and-low c bits.
__device__ __forceinline__ int vswz(int c, int key) {
  return key ^ ((((c >> 3) ^ c) & 7) << 3);
}

// -------- NCHW fp32 -> NHWC bf16 transpose; z<4: rgb->rgbN, z>=4: fre->freN -
__global__ void nhwc_all_kernel(const float* __restrict__ rgb, const float* __restrict__ fre,
                                unsigned short* __restrict__ rgbN, unsigned short* __restrict__ freN) {
  __shared__ unsigned short T[64][72];   // stride 144B (16B aligned rows)
  int p0 = blockIdx.x * 64, c0 = blockIdx.y * 64;
  int z = blockIdx.z;
  int bb = z & 3;
  const float* S = (z < 4 ? rgb : fre) + (size_t)bb * 384 * 36864;
  unsigned short* D = (z < 4 ? rgbN : freN) + (size_t)bb * 36864 * 384;
  int t = threadIdx.x;          // 256
  int pl = (t & 15) * 4;        // p offset (float4)
  int r0 = t >> 4;              // 16 c-rows per pass
#pragma unroll
  for (int k = 0; k < 4; ++k) {
    int c = r0 + 16 * k;
    float4 v = *(const float4*)&S[(size_t)(c0 + c) * 36864 + p0 + pl];
    T[pl + 0][c] = f2bf(v.x); T[pl + 1][c] = f2bf(v.y);
    T[pl + 2][c] = f2bf(v.z); T[pl + 3][c] = f2bf(v.w);
  }
  __syncthreads();
  int row = t >> 2, ch = (t & 3) * 16;
  ushort8 a = *(const ushort8*)&T[row][ch];
  ushort8 b = *(const ushort8*)&T[row][ch + 8];
  uint4* d = (uint4*)&D[(size_t)(p0 + row) * 384 + c0 + ch];
  d[0] = *(uint4*)&a; d[1] = *(uint4*)&b;
}

// ---------------- prep: fold BN into 1x1 weights, attn scale into q rows ----
__global__ void fold_qvk_kernel(const float* __restrict__ qv_w, const float* __restrict__ qv_b,
                                const float* __restrict__ k_w, const float* __restrict__ k_b,
                                const float* __restrict__ g, const float* __restrict__ be,
                                const float* __restrict__ mu, const float* __restrict__ var,
                                unsigned short* __restrict__ Wq, float* __restrict__ bq,
                                unsigned short* __restrict__ Wk, float* __restrict__ bk) {
  int o = blockIdx.x;            // 0..767 -> qv row, 768..1151 -> k row
  int t = threadIdx.x;           // 128
  bool isq = o < 768;
  int oo = isq ? o : o - 768;
  const float* wrow = isq ? qv_w + (size_t)oo * 384 : k_w + (size_t)oo * 384;
  float mul = (isq && oo < 384) ? 0.08838834764831845f : 1.0f;  // 1/sqrt(128) folded into q
  float acc = 0.f;
  for (int c = t; c < 384; c += 128) {
    float sc = g[c] * rsqrtf(var[c] + 1e-5f);
    float sh = be[c] - mu[c] * sc;
    float w = wrow[c];
    acc += w * sh;
    unsigned short wb = f2bf(w * sc * mul);
    if (isq) Wq[(size_t)oo * 384 + c] = wb; else Wk[(size_t)oo * 384 + c] = wb;
  }
#pragma unroll
  for (int m = 1; m < 64; m <<= 1) acc += __shfl_xor(acc, m);
  __shared__ float part[2];
  if ((t & 63) == 0) part[t >> 6] = acc;
  __syncthreads();
  if (t == 0) {
    float b0 = isq ? qv_b[oo] : k_b[oo];
    float bias = (b0 + part[0] + part[1]) * mul;
    if (isq) bq[oo] = bias; else bk[oo] = bias;
  }
}

// reorder oc_w (o,c,kh,kw) -> Wc[o][kq][c] bf16 ; compute output-BN scale/shift
__global__ void fold_oc_kernel(const float* __restrict__ oc_w,
                               const float* __restrict__ g, const float* __restrict__ be,
                               const float* __restrict__ mu, const float* __restrict__ var,
                               unsigned short* __restrict__ Wc, float* __restrict__ s_oc,
                               float* __restrict__ t_oc) {
  int idx = blockIdx.x * 256 + threadIdx.x;
  if (idx < 384) {
    float sc = g[idx] * rsqrtf(var[idx] + 1e-5f);
    s_oc[idx] = sc;
    t_oc[idx] = be[idx] - mu[idx] * sc;
  }
  if (idx < 384 * 3456) {
    int o = idx / 3456, r = idx % 3456;
    int kq = r / 384, c = r % 384;
    Wc[idx] = f2bf(oc_w[((size_t)o * 384 + c) * 9 + kq]);
  }
}

// ------- 1x1 GEMM device body: 2-phase dbuf g2l16, 256p x 128o, BK=32 ------
__device__ __forceinline__ void gemm1n_body(const unsigned short* __restrict__ XN,
                                            const unsigned short* __restrict__ W,
                                            const float* __restrict__ bias,
                                            unsigned short* __restrict__ Out,
                                            int OW, int OT, int bi,
                                            unsigned short* Ws2, unsigned short* Xs2) {
  int ot = bi % OT;                                // ot innermost: X panel L2 reuse
  int pt = (bi / OT) % 144;
  int bb = bi / (OT * 144);
  int obase = ot * 128, pbase = pt * 256;
  int tid = threadIdx.x;
  int wv = tid >> 6, lane = tid & 63;
  int l15 = lane & 15, lg = lane >> 4;
  int wc = wv & 1, wr = wv >> 1;
  f32x4 acc[4][4];
#pragma unroll
  for (int i = 0; i < 4; ++i)
#pragma unroll
    for (int j = 0; j < 4; ++j) acc[i][j] = 0.f;
  int rl = lane >> 2;
  int csw = (((lane & 3) ^ ((lane >> 3) & 3)) << 3);
  const unsigned short* Ap = W + (size_t)(obase + 16 * wv + rl) * 384 + csw;
  const unsigned short* XbN = XN + (size_t)bb * 36864 * 384;
  const unsigned short* Bp0 = XbN + (size_t)(pbase + 32 * wv + rl) * 384 + csw;
  const unsigned short* Bp1 = Bp0 + (size_t)16 * 384;
  int colsw = ((lg ^ ((l15 >> 1) & 3)) << 3);
  unsigned short* WsW = Ws2 + (16 * wv) * 32;
  unsigned short* XsW0 = Xs2 + (32 * wv) * 32;
  unsigned short* XsW1 = Xs2 + (32 * wv + 16) * 32;
  const int WBUF = 128 * 32, XBUF = 256 * 32;
  g2l16(Ap, WsW); g2l16(Bp0, XsW0); g2l16(Bp1, XsW1);
  Ap += 32; Bp0 += 32; Bp1 += 32;
  for (int t = 0; t < 12; ++t) {
    int cur = t & 1, nxt = cur ^ 1;
    if (t < 11) {
      g2l16(Ap, WsW + nxt * WBUF);
      g2l16(Bp0, XsW0 + nxt * XBUF);
      g2l16(Bp1, XsW1 + nxt * XBUF);
      Ap += 32; Bp0 += 32; Bp1 += 32;
      asm volatile("s_waitcnt vmcnt(3)" ::: "memory");
    } else {
      asm volatile("s_waitcnt vmcnt(0)" ::: "memory");
    }
    __builtin_amdgcn_s_barrier();
    __builtin_amdgcn_sched_barrier(0);
    const unsigned short* Wt = Ws2 + cur * WBUF;
    const unsigned short* Xt = Xs2 + cur * XBUF;
    short8 af[4], bf[4];
#pragma unroll
    for (int f = 0; f < 4; ++f) af[f] = *(const short8*)&Xt[(wr * 64 + f * 16 + l15) * 32 + colsw];
#pragma unroll
    for (int f = 0; f < 4; ++f) bf[f] = *(const short8*)&Wt[(wc * 64 + f * 16 + l15) * 32 + colsw];
#pragma unroll
    for (int fm = 0; fm < 4; ++fm)
#pragma unroll
      for (int fn = 0; fn < 4; ++fn)
        acc[fm][fn] = MFMA(af[fm], bf[fn], acc[fm][fn]);
    __builtin_amdgcn_s_barrier();
    __builtin_amdgcn_sched_barrier(0);
  }
  unsigned short* Ob = Out + (size_t)bb * 36864 * OW;
#pragma unroll
  for (int fn = 0; fn < 4; ++fn) {
    int o = obase + wc * 64 + fn * 16 + l15;
    float bsv = bias[o];
#pragma unroll
    for (int fm = 0; fm < 4; ++fm) {
#pragma unroll
      for (int r = 0; r < 4; ++r) {
        int p = pbase + wr * 64 + fm * 16 + lg * 4 + r;
        Ob[(size_t)p * OW + o] = f2bf(acc[fm][fn][r] + bsv);
      }
    }
  }
}

// merged: blocks [0,3456) = qv GEMM, [3456,5184) = k GEMM
__launch_bounds__(512)
__global__ void gemm1n_all_kernel(const unsigned short* __restrict__ rgbN,
                                  const unsigned short* __restrict__ freN,
                                  const unsigned short* __restrict__ Wq, const float* __restrict__ bq,
                                  const unsigned short* __restrict__ Wk, const float* __restrict__ bk,
                                  unsigned short* __restrict__ qvbuf, unsigned short* __restrict__ kbuf) {
  __shared__ unsigned short Ws2[2 * 128 * 32];
  __shared__ unsigned short Xs2[2 * 256 * 32];
  int bid = blockIdx.x;
  if (bid < 3456) {
    int bi = (bid & 7) * 432 + (bid >> 3);   // XCD-contiguous within segment
    gemm1n_body(rgbN, Wq, bq, qvbuf, 768, 6, bi, Ws2, Xs2);
  } else {
    int idx = bid - 3456;
    int bi = (idx & 7) * 216 + (idx >> 3);
    gemm1n_body(freN, Wk, bk, kbuf, 384, 3, bi, Ws2, Xs2);
  }
}

// ---------------- GEMM-1 fallback (fp32 NCHW input, round-1 path) ----------
__launch_bounds__(256)
__global__ void gemm1_kernel(const float* __restrict__ X, const unsigned short* __restrict__ W,
                             const float* __restrict__ bias, unsigned short* __restrict__ Out,
                             int OW, int OT) {
  int bi = blockIdx.x;
  int ot = bi % OT;
  int pt = (bi / OT) % 288;
  int bb = bi / (OT * 288);
  int obase = ot * 128, pbase = pt * 128;
  __shared__ unsigned short As[128 * 40];
  __shared__ unsigned short Bs[128 * 40];
  int tid = threadIdx.x;
  int wv = tid >> 6, lane = tid & 63;
  int l15 = lane & 15, lg = lane >> 4;
  int pw = (wv >> 1) * 64, ow = (wv & 1) * 64;
  f32x4 acc[4][4];
#pragma unroll
  for (int i = 0; i < 4; ++i)
#pragma unroll
    for (int j = 0; j < 4; ++j) acc[i][j] = 0.f;
  const float* Xb = X + (size_t)bb * 384 * 36864;
  int arow = tid >> 1, ahalf = tid & 1;
  int bp = tid & 127, bcg0 = tid >> 7;
  for (int ks = 0; ks < 12; ++ks) {
    int c0 = ks * 32;
    __syncthreads();
    {
      const uint4* s4 = (const uint4*)(W + (size_t)(obase + arow) * 384 + c0 + ahalf * 16);
      uint4 a0 = s4[0], a1 = s4[1];
      uint4* d = (uint4*)&As[arow * 40 + ahalf * 16];
      d[0] = a0; d[1] = a1;
    }
    {
#pragma unroll
      for (int q = 0; q < 2; ++q) {
        int cg = bcg0 + q * 2;
        int cc = c0 + cg * 8;
        const float* src = Xb + (size_t)cc * 36864 + pbase + bp;
        ushort8 t8;
#pragma unroll
        for (int j = 0; j < 8; ++j) t8[j] = f2bf(src[(size_t)j * 36864]);
        *(ushort8*)&Bs[bp * 40 + cg * 8] = t8;
      }
    }
    __syncthreads();
    short8 af[4], bf[4];
#pragma unroll
    for (int f = 0; f < 4; ++f) af[f] = *(const short8*)&Bs[(pw + f * 16 + l15) * 40 + lg * 8];
#pragma unroll
    for (int f = 0; f < 4; ++f) bf[f] = *(const short8*)&As[(ow + f * 16 + l15) * 40 + lg * 8];
#pragma unroll
    for (int fm = 0; fm < 4; ++fm)
#pragma unroll
      for (int fn = 0; fn < 4; ++fn)
        acc[fm][fn] = MFMA(af[fm], bf[fn], acc[fm][fn]);
  }
  unsigned short* Ob = Out + (size_t)bb * 36864 * OW;
#pragma unroll
  for (int fn = 0; fn < 4; ++fn) {
    int o = obase + ow + fn * 16 + l15;
    float bsv = bias[o];
#pragma unroll
    for (int fm = 0; fm < 4; ++fm) {
#pragma unroll
      for (int r = 0; r < 4; ++r) {
        int p = pbase + pw + fm * 16 + lg * 4 + r;
        Ob[(size_t)p * OW + o] = f2bf(acc[fm][fn][r] + bsv);
      }
    }
  }
}

// ---------------- windowed attention device body, MODE 0/1/2 ---------------
template <int MODE>
__device__ __forceinline__ void attn_body(int bi, const unsigned short* qv, const unsigned short* kx,
                                          const float* __restrict__ rgb,
                                          const unsigned short* __restrict__ rgbn,
                                          unsigned short* xout, int padded,
                                          unsigned short* Qs, unsigned short* Ks,
                                          unsigned short* Vst, unsigned short* Ps) {
  constexpr int GB = MODE * 128;
  constexpr int NKV = (MODE == 2) ? 4 : 1;
  constexpr int NKF = (MODE == 0) ? 1 : 4;
  int bb = bi / 576;
  int r5 = bi % 576;
  int tid = threadIdx.x;
  int wv = tid >> 6, lane = tid & 63;
  int l15 = lane & 15, lg = lane >> 4;

  int h0, w0, qtb;
  if (MODE == 0) { int wy = r5 / 12; int wxb = (r5 % 12) * 4; h0 = wy * 4; w0 = wxb * 4; qtb = 0; }
  else if (MODE == 1) { int wy = r5 / 24; int wx = r5 % 24; h0 = wy * 8; w0 = wx * 8; qtb = 0; }
  else { int win = r5 >> 2; int qt = r5 & 3; int wy = win / 12; int wx = win % 12; h0 = wy * 16; w0 = wx * 16; qtb = qt * 64; }

  auto tok2p = [&](int t) -> int {
    if (MODE == 0) { int lw = t >> 4, tt = t & 15; return (h0 + (tt >> 2)) * 192 + w0 + lw * 4 + (tt & 3); }
    else if (MODE == 1) { return (h0 + (t >> 3)) * 192 + w0 + (t & 7); }
    else { return (h0 + (t >> 4)) * 192 + w0 + (t & 15); }
  };

  const unsigned short* qvB = qv + (size_t)bb * 36864 * 768;
  const unsigned short* kB = kx + (size_t)bb * 36864 * 384;

  // stage Q (64 tokens x 128 c)
  for (int ch = tid; ch < 1024; ch += 256) {
    int tok = ch >> 4, c8 = (ch & 15) << 3;
    int p = tok2p(qtb + tok);
    uint4 v = *(const uint4*)(qvB + (size_t)p * 768 + GB + c8);
    *(uint4*)&Qs[tok * 128 + (c8 ^ ((tok & 7) << 3))] = v;
  }
  __syncthreads();
  short8 qf[4];
  {
    int qrow = wv * 16 + l15;
#pragma unroll
    for (int cs = 0; cs < 4; ++cs)
      qf[cs] = *(const short8*)&Qs[qrow * 128 + ((cs * 32 + lg * 8) ^ ((qrow & 7) << 3))];
  }

  float m[4], s[4];
#pragma unroll
  for (int r = 0; r < 4; ++r) { m[r] = -1e30f; s[r] = 0.f; }
  f32x4 oacc[8];
#pragma unroll
  for (int i = 0; i < 8; ++i) oacc[i] = 0.f;

  for (int kt = 0; kt < NKV; ++kt) {
    __syncthreads();
    for (int ch = tid; ch < 1024; ch += 256) {  // stage K tile
      int tok = ch >> 4, c8 = (ch & 15) << 3;
      int p = tok2p(kt * 64 + tok);
      uint4 v = *(const uint4*)(kB + (size_t)p * 384 + GB + c8);
      *(uint4*)&Ks[tok * 128 + (c8 ^ ((tok & 7) << 3))] = v;
    }
    for (int ch = tid; ch < 1024; ch += 256) {  // stage V tile (transposed)
      int key = ch >> 4, c8 = (ch & 15) << 3;
      int p = tok2p(kt * 64 + key);
      ushort8 v = *(const ushort8*)(qvB + (size_t)p * 768 + 384 + GB + c8);
#pragma unroll
      for (int j = 0; j < 8; ++j)
        Vst[(c8 + j) * 64 + vswz(c8 + j, key)] = v[j];
    }
    __syncthreads();

    f32x4 sc[NKF];
#pragma unroll
    for (int kfi = 0; kfi < NKF; ++kfi) {
      int kf = (MODE == 0) ? wv : kfi;
      int krow = kf * 16 + l15;
      f32x4 a; a = 0.f;
#pragma unroll
      for (int cs = 0; cs < 4; ++cs) {
        short8 kfr = *(const short8*)&Ks[krow * 128 + ((cs * 32 + lg * 8) ^ ((krow & 7) << 3))];
        a = MFMA(qf[cs], kfr, a);
      }
      sc[kfi] = a;
    }

    unsigned short* Pw = Ps + wv * (16 * 72);
    float pr[4][NKF];
#pragma unroll
    for (int r = 0; r < 4; ++r) {
      float mx = -1e30f;
#pragma unroll
      for (int kfi = 0; kfi < NKF; ++kfi) mx = fmaxf(mx, sc[kfi][r]);
#pragma unroll
      for (int d = 1; d < 16; d <<= 1) mx = fmaxf(mx, __shfl_xor(mx, d));
      float mn = fmaxf(m[r], mx);
      float f = __expf(m[r] - mn);
      float ls = 0.f;
#pragma unroll
      for (int kfi = 0; kfi < NKF; ++kfi) { float e = __expf(sc[kfi][r] - mn); pr[r][kfi] = e; ls += e; }
#pragma unroll
      for (int d = 1; d < 16; d <<= 1) ls += __shfl_xor(ls, d);
      s[r] = s[r] * f + ls;
      m[r] = mn;
#pragma unroll
      for (int ct = 0; ct < 8; ++ct) oacc[ct][r] *= f;
    }
#pragma unroll
    for (int r = 0; r < 4; ++r) {
      int prow = lg * 4 + r;
#pragma unroll
      for (int kfi = 0; kfi < NKF; ++kfi) {
        int pcol = (MODE == 0) ? l15 : kfi * 16 + l15;
        Pw[prow * 72 + pcol] = f2bf(pr[r][kfi]);
      }
      if (MODE == 0) Pw[prow * 72 + 16 + l15] = 0;
    }
    constexpr int nks = (MODE == 0) ? 1 : 2;
#pragma unroll
    for (int ks = 0; ks < nks; ++ks) {
      short8 pf = *(const short8*)&Pw[l15 * 72 + ks * 32 + lg * 8];
#pragma unroll
      for (int ct = 0; ct < 8; ++ct) {
        int c = ct * 16 + l15;
        short8 vf;
        if (MODE == 0) {
          if (lg < 2) vf = *(const short8*)&Vst[c * 64 + vswz(c, wv * 16 + lg * 8)];
          else vf = 0;
        } else {
          vf = *(const short8*)&Vst[c * 64 + vswz(c, ks * 32 + lg * 8)];
        }
        oacc[ct] = MFMA(pf, vf, oacc[ct]);
      }
    }
  }

  // epilogue: divide by sum, add residual, store x (bf16)
  const float* rgbB = rgb + (size_t)bb * 384 * 36864;
  const unsigned short* rgbNB = rgbn + (size_t)bb * 36864 * 384;
  unsigned short* xB = padded ? xout + (size_t)bb * 37636 * 384
                              : xout + (size_t)bb * 36864 * 768;
#pragma unroll
  for (int r = 0; r < 4; ++r) {
    int q64 = wv * 16 + lg * 4 + r;
    int p = tok2p(qtb + q64);
    float inv = 1.0f / s[r];
    size_t rowoff;
    if (padded) {
      int h = p / 192, w = p % 192;
      rowoff = (size_t)((h + 1) * 194 + (w + 1)) * 384;
    } else {
      rowoff = (size_t)p * 768;
    }
#pragma unroll
    for (int ct = 0; ct < 8; ++ct) {
      int c = GB + ct * 16 + l15;
      float res = padded ? bf2f(rgbNB[(size_t)p * 384 + c]) : rgbB[(size_t)c * 36864 + p];
      float val = oacc[ct][r] * inv + res;
      xB[rowoff + c] = f2bf(val);
    }
  }
}

// merged: blocks [0,2304) mode0, [2304,4608) mode1, [4608,6912) mode2
__launch_bounds__(256)
__global__ void attn_all_kernel(const unsigned short* qv, const unsigned short* kx,
                                const float* __restrict__ rgb, const unsigned short* __restrict__ rgbn,
                                unsigned short* xout, int padded) {
  __shared__ unsigned short Qs[64 * 128];
  __shared__ unsigned short Ks[64 * 128];
  __shared__ unsigned short Vst[128 * 64];
  __shared__ unsigned short Ps[4 * 16 * 72];
  int bid = blockIdx.x;
  if (bid < 2304)      attn_body<0>(bid,        qv, kx, rgb, rgbn, xout, padded, Qs, Ks, Vst, Ps);
  else if (bid < 4608) attn_body<1>(bid - 2304, qv, kx, rgb, rgbn, xout, padded, Qs, Ks, Vst, Ps);
  else                 attn_body<2>(bid - 4608, qv, kx, rgb, rgbn, xout, padded, Qs, Ks, Vst, Ps);
}

// ------- zero only the 1-pixel border of xpad ------------------------------
__global__ void zero_border_kernel(unsigned short* __restrict__ xpad) {
  int bi = blockIdx.x;            // 4 * 772
  int bb = bi / 772, i = bi % 772;
  int h, w;
  if (i < 194) { h = 0; w = i; }
  else if (i < 388) { h = 193; w = i - 194; }
  else if (i < 580) { w = 0; h = i - 388 + 1; }
  else { w = 193; h = i - 580 + 1; }
  int t = threadIdx.x;            // 64; 48 active
  if (t < 48) {
    uint4 z = {0, 0, 0, 0};
    uint4* row = (uint4*)(xpad + ((size_t)bb * 37636 + h * 194 + w) * 384);
    row[t] = z;
  }
}

// ------ 3x3 conv: 2-phase double-buffered g2l16, 128o x 256p, BK=32 --------
// (verified round-5 kernel, 450us / MfmaUtil 39% / 0 bank conflicts)
__launch_bounds__(512)
__global__ void conv3d_kernel(const unsigned short* __restrict__ Xp,  // [b][37636][384] zero-padded
                              const unsigned short* __restrict__ Wc,
                              const float* __restrict__ s_oc, const float* __restrict__ t_oc,
                              float* __restrict__ Out) {
  // XCD-contiguous remap, ot innermost (X panel reused by 3 consecutive blocks)
  int bid = blockIdx.x;
  int bi = (bid & 7) * 216 + (bid >> 3);
  int ot = bi % 3;
  int pt = (bi / 3) % 144;
  int bb = bi / 432;
  int obase = ot * 128, pbase = pt * 256;
  __shared__ unsigned short Ws2[2][128 * 32];
  __shared__ unsigned short Xs2[2][256 * 32];
  int tid = threadIdx.x;
  int wv = tid >> 6, lane = tid & 63;
  int l15 = lane & 15, lg = lane >> 4;
  int wc = wv & 1, wr = wv >> 1;
  f32x4 acc[4][4];
#pragma unroll
  for (int i = 0; i < 4; ++i)
#pragma unroll
    for (int j = 0; j < 4; ++j) acc[i][j] = 0.f;
  int rl = lane >> 2;
  int csw = (((lane & 3) ^ ((lane >> 3) & 3)) << 3);
  const unsigned short* Ap = Wc + (size_t)(obase + 16 * wv + rl) * 3456 + csw;
  int p0 = pbase + 32 * wv + rl;
  int p1 = p0 + 16;
  const unsigned short* Xb = Xp + (size_t)bb * 37636 * 384;
  const unsigned short* Bp0 = Xb + (size_t)((p0 / 192 + 1) * 194 + (p0 % 192 + 1) - 195) * 384 + csw;
  const unsigned short* Bp1 = Xb + (size_t)((p1 / 192 + 1) * 194 + (p1 % 192 + 1) - 195) * 384 + csw;
  int colsw = ((lg ^ ((l15 >> 1) & 3)) << 3);
  unsigned short* WsW = &Ws2[0][(16 * wv) * 32];
  unsigned short* XsW0 = &Xs2[0][(32 * wv) * 32];
  unsigned short* XsW1 = &Xs2[0][(32 * wv + 16) * 32];
  const int WBUF = 128 * 32, XBUF = 256 * 32;
  g2l16(Ap, WsW); g2l16(Bp0, XsW0); g2l16(Bp1, XsW1);
  Ap += 32; Bp0 += 32; Bp1 += 32;
  for (int t = 0; t < 108; ++t) {
    int cur = t & 1, nxt = cur ^ 1;
    if (t < 107) {
      g2l16(Ap, WsW + nxt * WBUF);
      g2l16(Bp0, XsW0 + nxt * XBUF);
      g2l16(Bp1, XsW1 + nxt * XBUF);
      Ap += 32; Bp0 += 32; Bp1 += 32;
      if (t == 34 || t == 70) { Bp0 += 73344; Bp1 += 73344; }
      asm volatile("s_waitcnt vmcnt(3)" ::: "memory");
    } else {
      asm volatile("s_waitcnt vmcnt(0)" ::: "memory");
    }
    __builtin_amdgcn_s_barrier();
    __builtin_amdgcn_sched_barrier(0);
    const unsigned short* Wt = &Ws2[cur][0];
    const unsigned short* Xt = &Xs2[cur][0];
    short8 af[4], bf2[4];
#pragma unroll
    for (int f = 0; f < 4; ++f) af[f] = *(const short8*)&Wt[(wc * 64 + f * 16 + l15) * 32 + colsw];
#pragma unroll
    for (int f = 0; f < 4; ++f) bf2[f] = *(const short8*)&Xt[(wr * 64 + f * 16 + l15) * 32 + colsw];
#pragma unroll
    for (int fm = 0; fm < 4; ++fm)
#pragma unroll
      for (int fn = 0; fn < 4; ++fn)
        acc[fm][fn] = MFMA(af[fm], bf2[fn], acc[fm][fn]);
    __builtin_amdgcn_s_barrier();
    __builtin_amdgcn_sched_barrier(0);
  }
  float* Ob = Out + (size_t)bb * 384 * 36864;
#pragma unroll
  for (int fm = 0; fm < 4; ++fm) {
#pragma unroll
    for (int r = 0; r < 4; ++r) {
      int o = obase + wc * 64 + fm * 16 + lg * 4 + r;
      float sv = s_oc[o], tv = t_oc[o];
#pragma unroll
      for (int fn = 0; fn < 4; ++fn) {
        int p = pbase + wr * 64 + fn * 16 + l15;
        float y = acc[fm][fn][r] * sv + tv;
        Ob[(size_t)o * 36864 + p] = (y >= 0.f) ? y : 0.2f * y;
      }
    }
  }
}

// ---------------- fallback 3x3 conv (bounds-checked, no padding) -----------
__launch_bounds__(256)
__global__ void conv3_kernel(const unsigned short* __restrict__ X,
                             const unsigned short* __restrict__ Wc,
                             const float* __restrict__ s_oc, const float* __restrict__ t_oc,
                             float* __restrict__ Out) {
  int bi = blockIdx.x;
  int pt = bi % 288;
  int ot = (bi / 288) % 3;
  int bb = bi / 864;
  int obase = ot * 128, pbase = pt * 128;
  __shared__ unsigned short As[128 * 40];
  __shared__ unsigned short Bs[128 * 40];
  int tid = threadIdx.x;
  int wv = tid >> 6, lane = tid & 63;
  int l15 = lane & 15, lg = lane >> 4;
  int ow = (wv & 1) * 64, pw = (wv >> 1) * 64;
  f32x4 acc[4][4];
#pragma unroll
  for (int i = 0; i < 4; ++i)
#pragma unroll
    for (int j = 0; j < 4; ++j) acc[i][j] = 0.f;
  int arow = tid >> 1, ahalf = tid & 1;
  int sp = pbase + arow;
  int sh = sp / 192, sw = sp % 192;
  const unsigned short* Xb = X + (size_t)bb * 36864 * 768;
  for (int ksi = 0; ksi < 108; ++ksi) {
    int kq = ksi / 12;
    int c0 = (ksi % 12) * 32;
    int dh = kq / 3 - 1, dw = kq % 3 - 1;
    __syncthreads();
    {
      const uint4* s4 = (const uint4*)(Wc + (size_t)(obase + arow) * 3456 + kq * 384 + c0 + ahalf * 16);
      uint4 a0 = s4[0], a1 = s4[1];
      uint4* d = (uint4*)&As[arow * 40 + ahalf * 16];
      d[0] = a0; d[1] = a1;
    }
    {
      int hh = sh + dh, ww2 = sw + dw;
      uint4 b0 = {0, 0, 0, 0}, b1 = {0, 0, 0, 0};
      if ((unsigned)hh < 192u && (unsigned)ww2 < 192u) {
        const uint4* s4 = (const uint4*)(Xb + (size_t)(hh * 192 + ww2) * 768 + c0 + ahalf * 16);
        b0 = s4[0]; b1 = s4[1];
      }
      uint4* d = (uint4*)&Bs[arow * 40 + ahalf * 16];
      d[0] = b0; d[1] = b1;
    }
    __syncthreads();
    short8 af[4], bf2[4];
#pragma unroll
    for (int f = 0; f < 4; ++f) af[f] = *(const short8*)&As[(ow + f * 16 + l15) * 40 + lg * 8];
#pragma unroll
    for (int f = 0; f < 4; ++f) bf2[f] = *(const short8*)&Bs[(pw + f * 16 + l15) * 40 + lg * 8];
#pragma unroll
    for (int fm = 0; fm < 4; ++fm)
#pragma unroll
      for (int fn = 0; fn < 4; ++fn)
        acc[fm][fn] = MFMA(af[fm], bf2[fn], acc[fm][fn]);
  }
  float* Ob = Out + (size_t)bb * 384 * 36864;
#pragma unroll
  for (int fm = 0; fm < 4; ++fm) {
#pragma unroll
    for (int r = 0; r < 4; ++r) {
      int o = obase + ow + fm * 16 + lg * 4 + r;
      float sv = s_oc[o], tv = t_oc[o];
#pragma unroll
      for (int fn = 0; fn < 4; ++fn) {
        int p = pbase + pw + fn * 16 + l15;
        float y = acc[fm][fn][r] * sv + tv;
        Ob[(size_t)o * 36864 + p] = (y >= 0.f) ? y : 0.2f * y;
      }
    }
  }
}

// ---------------- launch ----------------
extern "C" void kernel_launch(void* const* d_in, const int* in_sizes, int n_in,
                              void* d_out, int out_size, void* d_ws, size_t ws_size,
                              hipStream_t stream) {
  const float* rgb  = (const float*)d_in[0];
  const float* fre  = (const float*)d_in[1];
  const float* ng   = (const float*)d_in[2];
  const float* nb   = (const float*)d_in[3];
  const float* nm   = (const float*)d_in[4];
  const float* nv   = (const float*)d_in[5];
  const float* qv_w = (const float*)d_in[6];
  const float* qv_b = (const float*)d_in[7];
  const float* k_w  = (const float*)d_in[8];
  const float* k_b  = (const float*)d_in[9];
  const float* oc_w = (const float*)d_in[10];
  const float* oc_g = (const float*)d_in[11];
  const float* oc_b = (const float*)d_in[12];
  const float* oc_m = (const float*)d_in[13];
  const float* oc_v = (const float*)d_in[14];

  char* ws = (char*)d_ws;
  const size_t QV_B   = 226492416;   // 147456*768*2
  const size_t K_B    = 113246208;   // 147456*384*2
  const size_t XPAD_B = 115617792;   // 4*37636*384*2  (also holds freN: 113246208 <= this)
  const size_t RGBN_B = 113246208;   // 4*36864*384*2
  size_t off = 0;
  unsigned short* qvbuf = (unsigned short*)(ws + off); off += QV_B;
  unsigned short* kbuf  = (unsigned short*)(ws + off); off += K_B;
  size_t dyn_off = off;
  unsigned short* xpad = (unsigned short*)(ws + dyn_off);          // also freN
  unsigned short* rgbN = (unsigned short*)(ws + dyn_off + XPAD_B);
  const size_t WEIGHTS_B = 589824 + 294912 + 2654208 + 3072 + 1536 + 1536 + 1536;
  bool fast = (ws_size >= dyn_off + XPAD_B + RGBN_B + WEIGHTS_B);
  if (fast) off += XPAD_B + RGBN_B;
  unsigned short* Wq = (unsigned short*)(ws + off); off += 589824;
  unsigned short* Wk = (unsigned short*)(ws + off); off += 294912;
  unsigned short* Wc = (unsigned short*)(ws + off); off += 2654208;
  float* bq  = (float*)(ws + off); off += 3072;
  float* bk  = (float*)(ws + off); off += 1536;
  float* soc = (float*)(ws + off); off += 1536;
  float* toc = (float*)(ws + off); off += 1536;
  float* out = (float*)d_out;

  fold_qvk_kernel<<<dim3(1152), dim3(128), 0, stream>>>(qv_w, qv_b, k_w, k_b, ng, nb, nm, nv, Wq, bq, Wk, bk);
  fold_oc_kernel<<<dim3(5184), dim3(256), 0, stream>>>(oc_w, oc_g, oc_b, oc_m, oc_v, Wc, soc, toc);

  if (fast) {
    unsigned short* freN = xpad;  // region reused: freN dead before xpad written
    nhwc_all_kernel<<<dim3(576, 6, 8), dim3(256), 0, stream>>>(rgb, fre, rgbN, freN);
    gemm1n_all_kernel<<<dim3(5184), dim3(512), 0, stream>>>(rgbN, freN, Wq, bq, Wk, bk, qvbuf, kbuf);
    zero_border_kernel<<<dim3(4 * 772), dim3(64), 0, stream>>>(xpad);
    attn_all_kernel<<<dim3(6912), dim3(256), 0, stream>>>(qvbuf, kbuf, rgb, rgbN, xpad, 1);
    conv3d_kernel<<<dim3(1728), dim3(512), 0, stream>>>(xpad, Wc, soc, toc, out);
  } else {
    gemm1_kernel<<<dim3(4 * 288 * 6), dim3(256), 0, stream>>>(rgb, Wq, bq, qvbuf, 768, 6);
    gemm1_kernel<<<dim3(4 * 288 * 3), dim3(256), 0, stream>>>(fre, Wk, bk, kbuf, 384, 3);
    attn_all_kernel<<<dim3(6912), dim3(256), 0, stream>>>(qvbuf, kbuf, rgb, qvbuf, qvbuf, 0);
    conv3_kernel<<<dim3(4 * 3 * 288), dim3(256), 0, stream>>>(qvbuf, Wc, soc, toc, out);
  }
}